// Round 6
// baseline (1364.704 us; speedup 1.0000x reference)
//
#include <hip/hip_runtime.h>

#define NN 100000
#define EE 1600000
#define HH 128
#define MM 256
#define LL 6
#define GG 512
#define SCAN_NB ((NN + 1023) / 1024)

typedef __attribute__((ext_vector_type(8))) short short8;
typedef __attribute__((ext_vector_type(4))) float floatx4;

__device__ __forceinline__ float swishf(float v) {
    // v * rcp(1+e^-v): rcp is ~1ulp f32, invisible vs bf16 quantization downstream.
    return v * __builtin_amdgcn_rcpf(1.0f + __expf(-v));
}

__device__ __forceinline__ unsigned short f2bf(float f) {
    unsigned u = __builtin_bit_cast(unsigned, f);
    unsigned r = u + 0x7FFFu + ((u >> 16) & 1u);
    return (unsigned short)(r >> 16);
}

__device__ __forceinline__ float bf2f(unsigned short u) {
    return __builtin_bit_cast(float, (unsigned)u << 16);
}

__device__ __forceinline__ float2 bf2f2(unsigned u) {
    float2 r;
    r.x = __builtin_bit_cast(float, u << 16);
    r.y = __builtin_bit_cast(float, u & 0xFFFF0000u);
    return r;
}

// RNE pack of two f32 -> one u32 of 2 bf16 (lo = a, hi = b). Bit-identical to f2bf.
__device__ __forceinline__ unsigned cvt2bf(float a, float b) {
    unsigned r;
    asm("v_cvt_pk_bf16_f32 %0, %1, %2" : "=v"(r) : "v"(a), "v"(b));
    return r;
}

__device__ __forceinline__ void unpack8(uint4 v, float* a) {
    float2 p0 = bf2f2(v.x), p1 = bf2f2(v.y), p2 = bf2f2(v.z), p3 = bf2f2(v.w);
    a[0] = p0.x; a[1] = p0.y; a[2] = p1.x; a[3] = p1.y;
    a[4] = p2.x; a[5] = p2.y; a[6] = p3.x; a[7] = p3.y;
}

__device__ __forceinline__ uint4 pack8(const float* o) {
    uint4 pk;
    pk.x = cvt2bf(o[0], o[1]);
    pk.y = cvt2bf(o[2], o[3]);
    pk.z = cvt2bf(o[4], o[5]);
    pk.w = cvt2bf(o[6], o[7]);
    return pk;
}

__device__ __forceinline__ uint2 pack4(const float* o) {
    uint2 pk;
    pk.x = cvt2bf(o[0], o[1]);
    pk.y = cvt2bf(o[2], o[3]);
    return pk;
}

// h[n,c] (row-major bf16) = z_embed[z[n],c] + x[:,1:]@ew^T + eb
__global__ void k_embed(const float* __restrict__ x, const float* __restrict__ z_embed,
                        const float* __restrict__ ew, const float* __restrict__ eb,
                        unsigned short* __restrict__ hb) {
    int idx = blockIdx.x * blockDim.x + threadIdx.x;
    if (idx >= NN * 32) return;
    int n = idx >> 5;
    int c0 = (idx & 31) << 2;
    const float* xr = x + (size_t)n * 4;
    int z = (int)xr[0];
    float x1 = xr[1], x2 = xr[2], x3 = xr[3];
    const float* ze = z_embed + (size_t)z * HH + c0;
    float o[4];
#pragma unroll
    for (int j = 0; j < 4; ++j) {
        int c = c0 + j;
        o[j] = ze[j] + x1 * ew[c * 3 + 0] + x2 * ew[c * 3 + 1] + x3 * ew[c * 3 + 2] + eb[c];
    }
    *(uint2*)(hb + (size_t)n * HH + c0) = pack4(o);
}

__global__ void k_f2bf3(const float* __restrict__ s1, unsigned short* __restrict__ d1, int n1,
                        const float* __restrict__ s2, unsigned short* __restrict__ d2, int n2,
                        const float* __restrict__ s3, unsigned short* __restrict__ d3, int n3) {
    int i = blockIdx.x * blockDim.x + threadIdx.x;
    if (i < n1) {
        d1[i] = f2bf(s1[i]);
    } else if (i < n1 + n2) {
        d2[i - n1] = f2bf(s2[i - n1]);
    } else if (i < n1 + n2 + n3) {
        d3[i - n1 - n2] = f2bf(s3[i - n1 - n2]);
    }
}

__global__ __launch_bounds__(256) void k_degree_p(const int* __restrict__ dst,
                                                  int* __restrict__ deg) {
    int part = blockIdx.x & 7;
    int blk = blockIdx.x >> 3;
    int nb = gridDim.x >> 3;
    int lo = (int)((long long)part * NN / 8);
    int hi = (int)((long long)(part + 1) * NN / 8);
    for (int e = blk * 256 + threadIdx.x; e < EE; e += nb * 256) {
        int d = dst[e];
        if (d >= lo && d < hi) atomicAdd(&deg[d], 1);
    }
}

__global__ void k_dinv(const int* __restrict__ deg, float* __restrict__ dinv) {
    int n = blockIdx.x * blockDim.x + threadIdx.x;
    if (n < NN) dinv[n] = rsqrtf((float)(deg[n] + 1));
}

__global__ void k_scan1(const int* __restrict__ deg, int* __restrict__ bsum) {
    __shared__ int sd[256];
    int t = threadIdx.x;
    int base = blockIdx.x * 1024 + t * 4;
    int s = 0;
#pragma unroll
    for (int j = 0; j < 4; ++j) {
        int i = base + j;
        if (i < NN) s += deg[i];
    }
    sd[t] = s;
    __syncthreads();
    for (int off = 128; off > 0; off >>= 1) {
        if (t < off) sd[t] += sd[t + off];
        __syncthreads();
    }
    if (t == 0) bsum[blockIdx.x] = sd[0];
}

__global__ void k_scan2(const int* __restrict__ bsum, int* __restrict__ boff) {
    __shared__ int sd[128];
    int t = threadIdx.x;
    int v = (t < SCAN_NB) ? bsum[t] : 0;
    sd[t] = v;
    __syncthreads();
    for (int off = 1; off < 128; off <<= 1) {
        int u = (t >= off) ? sd[t - off] : 0;
        __syncthreads();
        sd[t] += u;
        __syncthreads();
    }
    boff[t] = sd[t] - v;  // exclusive
}

__global__ void k_scan3(const int* __restrict__ deg, const int* __restrict__ boff,
                        int* __restrict__ rowptr) {
    __shared__ int sd[256];
    int t = threadIdx.x;
    int base = blockIdx.x * 1024 + t * 4;
    int v[4];
    int s = 0;
#pragma unroll
    for (int j = 0; j < 4; ++j) {
        int i = base + j;
        v[j] = (i < NN) ? deg[i] : 0;
        s += v[j];
    }
    sd[t] = s;
    __syncthreads();
    for (int off = 1; off < 256; off <<= 1) {
        int u = (t >= off) ? sd[t - off] : 0;
        __syncthreads();
        sd[t] += u;
        __syncthreads();
    }
    int run = boff[blockIdx.x] + sd[t] - s;
#pragma unroll
    for (int j = 0; j < 4; ++j) {
        int i = base + j;
        if (i < NN) rowptr[i] = run;
        if (i == NN - 1) rowptr[NN] = run + v[j];
        run += v[j];
    }
}

__global__ __launch_bounds__(256) void k_fill_p(const int* __restrict__ ei,
                                                const int* __restrict__ rowptr,
                                                int* __restrict__ cursor,
                                                int* __restrict__ col) {
    int part = blockIdx.x & 7;
    int blk = blockIdx.x >> 3;
    int nb = gridDim.x >> 3;
    int lo = (int)((long long)part * NN / 8);
    int hi = (int)((long long)(part + 1) * NN / 8);
    for (int e = blk * 256 + threadIdx.x; e < EE; e += nb * 256) {
        int d = ei[EE + e];
        if (d >= lo && d < hi) {
            int p = atomicAdd(&cursor[d], 1);
            col[rowptr[d] + p] = ei[e];
        }
    }
}

__global__ void k_gptr(const int* __restrict__ batch, int* __restrict__ gptr) {
    int n = blockIdx.x * blockDim.x + threadIdx.x;
    if (n >= NN) return;
    int b = batch[n];
    int pb = (n == 0) ? -1 : batch[n - 1];
    for (int g = pb + 1; g <= b; ++g) gptr[g] = n;
    if (n == NN - 1) {
        for (int g = b + 1; g <= GG; ++g) gptr[g] = NN;
    }
}

// Conv GEMM (layer 0 only): y = bf16((h @ Wc^T) * dinv[row]).
__global__ __launch_bounds__(256) void k_conv(const unsigned short* __restrict__ A,
                                              const unsigned short* __restrict__ B,
                                              const float* __restrict__ dinv,
                                              unsigned short* __restrict__ Cb) {
    __shared__ unsigned short Bs[128][HH + 8];
    const int tid = threadIdx.x;
    const int wave = tid >> 6;
    const int lane = tid & 63;
    const int quad = lane >> 4;
    const int l16 = lane & 15;
    const int wr = (wave & 1) << 6;
    const int wc = (wave >> 1) << 6;
    const int rowBase = blockIdx.x * 128;

    for (int i = tid; i < 128 * (HH / 8); i += 256) {
        int r = i / (HH / 8);
        int kk = (i % (HH / 8)) * 8;
        int rho = (r & 64) | ((r & 3) << 4) | ((r >> 2) & 15);
        *(uint4*)(&Bs[rho][kk]) = *(const uint4*)(B + (size_t)r * HH + kk);
    }

    floatx4 acc[4][4];
    const floatx4 zed = {0.f, 0.f, 0.f, 0.f};
#pragma unroll
    for (int i = 0; i < 4; ++i)
#pragma unroll
        for (int j = 0; j < 4; ++j) acc[i][j] = zed;

    int ar[4];
#pragma unroll
    for (int i = 0; i < 4; ++i) {
        int r = rowBase + wr + (i << 4) + l16;
        ar[i] = r < NN ? r : NN - 1;
    }

    __syncthreads();

#pragma unroll
    for (int ks = 0; ks < HH / 32; ++ks) {
        int k = (ks << 5) + (quad << 3);
        short8 a[4], b[4];
#pragma unroll
        for (int i = 0; i < 4; ++i) a[i] = *(const short8*)(A + (size_t)ar[i] * HH + k);
#pragma unroll
        for (int j = 0; j < 4; ++j) b[j] = *(const short8*)(&Bs[wc + (j << 4) + l16][k]);
#pragma unroll
        for (int i = 0; i < 4; ++i)
#pragma unroll
            for (int j = 0; j < 4; ++j)
                acc[i][j] =
                    __builtin_amdgcn_mfma_f32_16x16x32_bf16(a[i], b[j], acc[i][j], 0, 0, 0);
    }

    const int c0 = wc + (l16 << 2);
#pragma unroll
    for (int i = 0; i < 4; ++i) {
        int rb = rowBase + wr + (i << 4) + (quad << 2);
#pragma unroll
        for (int reg = 0; reg < 4; ++reg) {
            int r = rb + reg;
            if (r < NN) {
                float dv = dinv[r];
                float o[4];
#pragma unroll
                for (int j = 0; j < 4; ++j) o[j] = acc[i][j][reg] * dv;
                *(uint2*)(Cb + (size_t)r * HH + c0) = pack4(o);
            }
        }
    }
}

// Gather + fused per-graph stats. Wave = 4 consecutive nodes (block = 16; NN%16==0).
// Edge loop unrolled x4: 4 col reads + 4 256B row gathers in flight before
// consumption (quadruples MLP on the latency-exposed gather path).
__global__ __launch_bounds__(256) void k_agg(const unsigned short* __restrict__ y,
                                             const int* __restrict__ rowptr,
                                             const int* __restrict__ col,
                                             const float* __restrict__ dinv,
                                             const float* __restrict__ cb,
                                             const int* __restrict__ batch,
                                             unsigned short* __restrict__ agg,
                                             float* __restrict__ S1g,
                                             float* __restrict__ S2g) {
    __shared__ float s1s[4][128];
    __shared__ float s2s[4][128];
    __shared__ int sg[4];
    int w = threadIdx.x >> 6;
    int lane = threadIdx.x & 63;
    int grp = lane >> 4;
    int l16 = lane & 15;
    const uint4* yv = (const uint4*)y;
    const int dbase = blockIdx.x * 16 + w * 4;

    // conv bias is dispatch-invariant: hoist
    float cbv[8];
    {
        float4 c0 = *(const float4*)(cb + l16 * 8);
        float4 c1 = *(const float4*)(cb + l16 * 8 + 4);
        cbv[0] = c0.x; cbv[1] = c0.y; cbv[2] = c0.z; cbv[3] = c0.w;
        cbv[4] = c1.x; cbv[5] = c1.y; cbv[6] = c1.z; cbv[7] = c1.w;
    }

    float sA[8], sB[8];
#pragma unroll
    for (int j = 0; j < 8; ++j) { sA[j] = 0.f; sB[j] = 0.f; }
    int gcur = -1;

    for (int i = 0; i < 4; ++i) {
        int d = dbase + i;  // always < NN (NN % 16 == 0)
        float acc[8];
#pragma unroll
        for (int j = 0; j < 8; ++j) acc[j] = 0.f;
        if (grp == 0) {
            uint4 v = yv[(size_t)d * 16 + l16];
            unpack8(v, acc);
        }
        int beg = rowptr[d];
        int end = rowptr[d + 1];
        int e = beg + grp;
        for (; e + 12 < end; e += 16) {
            int s0 = col[e];
            int s1 = col[e + 4];
            int s2 = col[e + 8];
            int s3 = col[e + 12];
            uint4 v0 = yv[(size_t)s0 * 16 + l16];
            uint4 v1 = yv[(size_t)s1 * 16 + l16];
            uint4 v2 = yv[(size_t)s2 * 16 + l16];
            uint4 v3 = yv[(size_t)s3 * 16 + l16];
            float b0[8], b1[8], b2[8], b3[8];
            unpack8(v0, b0);
            unpack8(v1, b1);
            unpack8(v2, b2);
            unpack8(v3, b3);
#pragma unroll
            for (int k = 0; k < 8; ++k) acc[k] += (b0[k] + b1[k]) + (b2[k] + b3[k]);
        }
        for (; e < end; e += 4) {
            int s0 = col[e];
            uint4 v0 = yv[(size_t)s0 * 16 + l16];
            float b0[8];
            unpack8(v0, b0);
#pragma unroll
            for (int k = 0; k < 8; ++k) acc[k] += b0[k];
        }
#pragma unroll
        for (int j = 0; j < 8; ++j) {
            acc[j] += __shfl_xor(acc[j], 16, 64);
            acc[j] += __shfl_xor(acc[j], 32, 64);
        }
        if (grp == 0) {
            float dv = dinv[d];
            float o[8];
#pragma unroll
            for (int j = 0; j < 8; ++j) o[j] = acc[j] * dv + cbv[j];
            uint4 pk = pack8(o);
            *(uint4*)(agg + (size_t)d * HH + l16 * 8) = pk;
            float2 q0 = bf2f2(pk.x), q1 = bf2f2(pk.y), q2 = bf2f2(pk.z), q3 = bf2f2(pk.w);
            float orv[8] = {q0.x, q0.y, q1.x, q1.y, q2.x, q2.y, q3.x, q3.y};
            int g = batch[d];
            if (g != gcur) {
                if (gcur >= 0) {
#pragma unroll
                    for (int j = 0; j < 8; ++j) {
                        atomicAdd(&S1g[gcur * HH + l16 * 8 + j], sA[j]);
                        atomicAdd(&S2g[gcur * HH + l16 * 8 + j], sB[j]);
                    }
                }
                gcur = g;
#pragma unroll
                for (int j = 0; j < 8; ++j) {
                    sA[j] = orv[j];
                    sB[j] = orv[j] * orv[j];
                }
            } else {
#pragma unroll
                for (int j = 0; j < 8; ++j) {
                    sA[j] += orv[j];
                    sB[j] += orv[j] * orv[j];
                }
            }
        }
    }

    if (grp == 0) {
#pragma unroll
        for (int j = 0; j < 8; ++j) {
            s1s[w][l16 * 8 + j] = sA[j];
            s2s[w][l16 * 8 + j] = sB[j];
        }
        if (l16 == 0) sg[w] = gcur;
    }
    __syncthreads();
    if (threadIdx.x < 128) {
        int c = threadIdx.x;
        int g0 = sg[0], g1 = sg[1], g2 = sg[2], g3 = sg[3];
        if (g0 >= 0 && g0 == g1 && g0 == g2 && g0 == g3) {
            float a = (s1s[0][c] + s1s[1][c]) + (s1s[2][c] + s1s[3][c]);
            float b = (s2s[0][c] + s2s[1][c]) + (s2s[2][c] + s2s[3][c]);
            atomicAdd(&S1g[g0 * HH + c], a);
            atomicAdd(&S2g[g0 * HH + c], b);
        } else {
            int gs[4] = {g0, g1, g2, g3};
#pragma unroll
            for (int ww = 0; ww < 4; ++ww) {
                if (gs[ww] >= 0) {
                    atomicAdd(&S1g[gs[ww] * HH + c], s1s[ww][c]);
                    atomicAdd(&S2g[gs[ww] * HH + c], s2s[ww][c]);
                }
            }
        }
    }
}

// finalize: c1 = gamma*rstd, c0 = beta - c1*ms*mean (per-layer S buffers; no re-zero)
__global__ __launch_bounds__(128) void k_finalize(const int* __restrict__ gptr,
                                                  const float* __restrict__ ms,
                                                  const float* __restrict__ gamma,
                                                  const float* __restrict__ beta,
                                                  const float* __restrict__ S1g,
                                                  const float* __restrict__ S2g,
                                                  float* __restrict__ c1,
                                                  float* __restrict__ c0) {
    int g = blockIdx.x;
    int c = threadIdx.x;
    int cnt = gptr[g + 1] - gptr[g];
    float inv = 1.0f / (float)(cnt > 0 ? cnt : 1);
    float S1 = S1g[g * HH + c];
    float S2 = S2g[g * HH + c];
    float m = S1 * inv;
    float msc = ms[c];
    float var = S2 * inv - msc * (2.0f - msc) * m * m;
    float rstd = rsqrtf(var + 1e-5f);
    float c1v = gamma[c] * rstd;
    c1[g * HH + c] = c1v;
    c0[g * HH + c] = beta[c] - c1v * msc * m;
}

// Mega layer kernel v6: BARRIER-FREE. Block = 1 wave (64 threads), 32 rows.
// No inter-wave deps -> zero __syncthreads; LDS is wave-private (lgkmcnt-ordered).
// Grid = NN/32 = 3125 exactly (NN%32==0) -> no row guards needed.
// Phase 0: ha = swish(c1*agg + c0) -> ha_s[32][136].
// Chunks c=0..3 (64 t-cols each): A-GEMM acc1[2][4] (t-col = 64c + 4*l16 + j),
//   swish -> ts[32][72]; B-GEMM acc2[2][8] += ts @ W2[:,64c:+64]^T (out-col = 8*l16+jo).
// Epilogue: h' = swish(acc2+b2)+hb (read adjacent to write, r3 lesson) -> hb/ha_s or h_out.
// Phase C (doConv): y = bf16((h' @ Wc^T)*dinv), out-col = 8*l16+jc.
__global__ __launch_bounds__(64, 3) void k_mega(const unsigned short* __restrict__ agg,
                                                const int* __restrict__ batch,
                                                const float* __restrict__ c1,
                                                const float* __restrict__ c0,
                                                const unsigned short* __restrict__ W1,
                                                const float* __restrict__ b1,
                                                const unsigned short* __restrict__ W2,
                                                const float* __restrict__ b2,
                                                const unsigned short* __restrict__ Wc,
                                                const float* __restrict__ dinv,
                                                unsigned short* __restrict__ hb,
                                                float* __restrict__ h_out,
                                                unsigned short* __restrict__ y_out,
                                                int writeF, int doConv) {
    __shared__ unsigned short ha_s[32 * 136];  // ha, then h' (pitch 136)
    __shared__ unsigned short ts[32 * 72];     // one 64-col chunk of t (pitch 72)
    const int tid = threadIdx.x;  // 0..63
    const int quad = tid >> 4;
    const int l16 = tid & 15;
    const int rowBase = blockIdx.x * 32;
    const int co8 = l16 << 3;  // 8 adjacent out-cols per lane (B/C phases)
    const floatx4 zed = {0.f, 0.f, 0.f, 0.f};

    // ---- phase 0: normswish -> ha_s (32 rows x 128 cols / 64 threads) ----
    {
        int lr = tid >> 1;           // 0..31
        int coff = (tid & 1) << 6;   // 0 / 64
        int r = rowBase + lr;
        int g = batch[r];
        const float* c1p = c1 + g * HH + coff;
        const float* c0p = c0 + g * HH + coff;
#pragma unroll
        for (int q = 0; q < 8; ++q) {
            uint4 raw = *(const uint4*)(agg + (size_t)r * HH + coff + (q << 3));
            float v[8];
            unpack8(raw, v);
            float4 ca = *(const float4*)(c1p + (q << 3));
            float4 cb4 = *(const float4*)(c1p + (q << 3) + 4);
            float4 da = *(const float4*)(c0p + (q << 3));
            float4 db = *(const float4*)(c0p + (q << 3) + 4);
            float cc1[8] = {ca.x, ca.y, ca.z, ca.w, cb4.x, cb4.y, cb4.z, cb4.w};
            float cc0[8] = {da.x, da.y, da.z, da.w, db.x, db.y, db.z, db.w};
            float o[8];
#pragma unroll
            for (int j = 0; j < 8; ++j) o[j] = swishf(cc1[j] * v[j] + cc0[j]);
            *(uint4*)(&ha_s[lr * 136 + coff + (q << 3)]) = pack8(o);
        }
    }
    // no barrier: single wave, compiler orders LDS via lgkmcnt

    floatx4 acc2[2][8];
#pragma unroll
    for (int i = 0; i < 2; ++i)
#pragma unroll
        for (int j = 0; j < 8; ++j) acc2[i][j] = zed;

#pragma unroll
    for (int c = 0; c < 4; ++c) {
        // ---- A chunk c: t[:, 64c + 4*l16 + j] = swish(ha @ W1^T + b1) ----
        floatx4 acc1[2][4];
#pragma unroll
        for (int i = 0; i < 2; ++i)
#pragma unroll
            for (int j = 0; j < 4; ++j) acc1[i][j] = zed;
        const int tco = (c << 6) + (l16 << 2);  // global t-col base for this lane
#pragma unroll
        for (int ks = 0; ks < 4; ++ks) {
            int k = (ks << 5) + (quad << 3);
            short8 a[2], b[4];
#pragma unroll
            for (int i = 0; i < 2; ++i)
                a[i] = *(const short8*)(&ha_s[((i << 4) + l16) * 136 + k]);
#pragma unroll
            for (int j = 0; j < 4; ++j)
                b[j] = *(const short8*)(W1 + (size_t)(tco + j) * HH + k);
#pragma unroll
            for (int i = 0; i < 2; ++i)
#pragma unroll
                for (int j = 0; j < 4; ++j)
                    acc1[i][j] = __builtin_amdgcn_mfma_f32_16x16x32_bf16(a[i], b[j],
                                                                         acc1[i][j], 0, 0, 0);
        }
        float4 b4 = *(const float4*)(b1 + tco);
        float bv1[4] = {b4.x, b4.y, b4.z, b4.w};
#pragma unroll
        for (int i = 0; i < 2; ++i) {
#pragma unroll
            for (int reg = 0; reg < 4; ++reg) {
                int lr = (i << 4) + (quad << 2) + reg;
                float o[4];
#pragma unroll
                for (int j = 0; j < 4; ++j) o[j] = swishf(acc1[i][j][reg] + bv1[j]);
                *(uint2*)(&ts[lr * 72 + (l16 << 2)]) = pack4(o);
            }
        }

        // ---- B chunk c: acc2 += t_chunk @ W2[:, 64c:+64]^T ----
#pragma unroll
        for (int ks = 0; ks < 2; ++ks) {
            int k = (ks << 5) + (quad << 3);
            short8 a[2], b[8];
#pragma unroll
            for (int i = 0; i < 2; ++i)
                a[i] = *(const short8*)(&ts[((i << 4) + l16) * 72 + k]);
#pragma unroll
            for (int jo = 0; jo < 8; ++jo)
                b[jo] = *(const short8*)(W2 + (size_t)(co8 + jo) * MM + (c << 6) + k);
#pragma unroll
            for (int i = 0; i < 2; ++i)
#pragma unroll
                for (int jo = 0; jo < 8; ++jo)
                    acc2[i][jo] = __builtin_amdgcn_mfma_f32_16x16x32_bf16(a[i], b[jo],
                                                                          acc2[i][jo], 0, 0, 0);
        }
    }

    // ---- epilogue: h' = swish(acc2 + b2) + res ----
    {
        float4 e0 = *(const float4*)(b2 + co8);
        float4 e1 = *(const float4*)(b2 + co8 + 4);
        float bv[8] = {e0.x, e0.y, e0.z, e0.w, e1.x, e1.y, e1.z, e1.w};
#pragma unroll
        for (int i = 0; i < 2; ++i) {
#pragma unroll
            for (int reg = 0; reg < 4; ++reg) {
                int lr = (i << 4) + (quad << 2) + reg;
                int r = rowBase + lr;
                uint4 rv = *(const uint4*)(hb + (size_t)r * HH + co8);
                float rr[8];
                unpack8(rv, rr);
                float o[8];
#pragma unroll
                for (int j = 0; j < 8; ++j)
                    o[j] = swishf(acc2[i][j][reg] + bv[j]) + rr[j];
                if (doConv) {
                    uint4 pk = pack8(o);
                    *(uint4*)(hb + (size_t)r * HH + co8) = pk;
                    *(uint4*)(&ha_s[lr * 136 + co8]) = pk;
                } else {
                    *(float4*)(h_out + (size_t)r * HH + co8) =
                        make_float4(o[0], o[1], o[2], o[3]);
                    *(float4*)(h_out + (size_t)r * HH + co8 + 4) =
                        make_float4(o[4], o[5], o[6], o[7]);
                }
            }
        }
    }

    // ---- phase C: y_next = bf16((h' @ Wc^T) * dinv) ----
    if (doConv) {
        floatx4 acc3[2][8];
#pragma unroll
        for (int i = 0; i < 2; ++i)
#pragma unroll
            for (int j = 0; j < 8; ++j) acc3[i][j] = zed;
#pragma unroll
        for (int ks = 0; ks < 4; ++ks) {
            int k = (ks << 5) + (quad << 3);
            short8 a[2], b[8];
#pragma unroll
            for (int i = 0; i < 2; ++i)
                a[i] = *(const short8*)(&ha_s[((i << 4) + l16) * 136 + k]);
#pragma unroll
            for (int jc = 0; jc < 8; ++jc)
                b[jc] = *(const short8*)(Wc + (size_t)(co8 + jc) * HH + k);
#pragma unroll
            for (int i = 0; i < 2; ++i)
#pragma unroll
                for (int jc = 0; jc < 8; ++jc)
                    acc3[i][jc] = __builtin_amdgcn_mfma_f32_16x16x32_bf16(a[i], b[jc],
                                                                          acc3[i][jc], 0, 0, 0);
        }
#pragma unroll
        for (int i = 0; i < 2; ++i) {
#pragma unroll
            for (int reg = 0; reg < 4; ++reg) {
                int r = rowBase + (i << 4) + (quad << 2) + reg;
                float dv = dinv[r];
                float o[8];
#pragma unroll
                for (int j = 0; j < 8; ++j) o[j] = acc3[i][j][reg] * dv;
                *(uint4*)(y_out + (size_t)r * HH + co8) = pack8(o);
            }
        }
    }
}

extern "C" void kernel_launch(void* const* d_in, const int* in_sizes, int n_in,
                              void* d_out, int out_size, void* d_ws, size_t ws_size,
                              hipStream_t stream) {
    const float* x = (const float*)d_in[0];
    const int* ei = (const int*)d_in[1];
    const int* batch = (const int*)d_in[2];
    const float* z_embed = (const float*)d_in[3];
    const float* extra_w = (const float*)d_in[4];
    const float* extra_b = (const float*)d_in[5];
    const float* conv_w = (const float*)d_in[6];
    const float* conv_b = (const float*)d_in[7];
    const float* gamma = (const float*)d_in[8];
    const float* beta = (const float*)d_in[9];
    const float* mean_scale = (const float*)d_in[10];
    const float* mlp_w1 = (const float*)d_in[11];
    const float* mlp_b1 = (const float*)d_in[12];
    const float* mlp_w2 = (const float*)d_in[13];
    const float* mlp_b2 = (const float*)d_in[14];
    float* h_out = (float*)d_out;

    char* wsB = (char*)d_ws;
    size_t off = 0;
    auto alloc = [&](size_t bytes) -> void* {
        void* p = (void*)(wsB + off);
        off = (off + bytes + 255) & ~(size_t)255;
        return p;
    };
    float* dinv = (float*)alloc((size_t)NN * 4);
    int* deg = (int*)alloc((size_t)NN * 4);
    int* cursor = (int*)alloc((size_t)NN * 4);
    int* rowptr = (int*)alloc((size_t)(NN + 1) * 4);
    int* bsum = (int*)alloc(128 * 4);
    int* boff = (int*)alloc(128 * 4);
    int* col = (int*)alloc((size_t)EE * 4);
    int* gptr = (int*)alloc((size_t)(GG + 1) * 4);
    float* c1t = (float*)alloc((size_t)GG * HH * 4);
    float* c0t = (float*)alloc((size_t)GG * HH * 4);
    float* S1g6 = (float*)alloc((size_t)LL * GG * HH * 4);  // per-layer stats, zeroed once
    float* S2g6 = (float*)alloc((size_t)LL * GG * HH * 4);
    unsigned short* wb =
        (unsigned short*)alloc((size_t)(LL * (HH * HH + MM * HH + HH * MM)) * 2);
    unsigned short* cwb = wb;
    unsigned short* w1b = wb + (size_t)LL * HH * HH;
    unsigned short* w2b = w1b + (size_t)LL * MM * HH;
    unsigned short* hb = (unsigned short*)alloc((size_t)NN * HH * 2);    // bf16 residual
    unsigned short* ybuf = (unsigned short*)alloc((size_t)NN * HH * 2);  // y (conv out)
    unsigned short* aggb = (unsigned short*)alloc((size_t)NN * HH * 2);  // agg bf16

    hipMemsetAsync(deg, 0, (size_t)NN * 4, stream);
    hipMemsetAsync(cursor, 0, (size_t)NN * 4, stream);
    hipMemsetAsync(S1g6, 0, (size_t)LL * GG * HH * 4, stream);
    hipMemsetAsync(S2g6, 0, (size_t)LL * GG * HH * 4, stream);

    k_embed<<<(NN * 32 + 255) / 256, 256, 0, stream>>>(x, z_embed, extra_w, extra_b, hb);
    {
        int n1 = LL * HH * HH, n2 = LL * MM * HH, n3 = LL * HH * MM;
        int nt = n1 + n2 + n3;
        k_f2bf3<<<(nt + 255) / 256, 256, 0, stream>>>(conv_w, cwb, n1, mlp_w1, w1b, n2,
                                                      mlp_w2, w2b, n3);
    }
    k_degree_p<<<1024, 256, 0, stream>>>(ei + EE, deg);
    k_dinv<<<(NN + 255) / 256, 256, 0, stream>>>(deg, dinv);
    k_scan1<<<SCAN_NB, 256, 0, stream>>>(deg, bsum);
    k_scan2<<<1, 128, 0, stream>>>(bsum, boff);
    k_scan3<<<SCAN_NB, 256, 0, stream>>>(deg, boff, rowptr);
    k_fill_p<<<1024, 256, 0, stream>>>(ei, rowptr, cursor, col);
    k_gptr<<<(NN + 255) / 256, 256, 0, stream>>>(batch, gptr);

    int gconv = (NN + 127) / 128;
    int gmega = NN / 32;  // 3125, exact
    k_conv<<<gconv, 256, 0, stream>>>(hb, cwb, dinv, ybuf);
    for (int i = 0; i < LL; ++i) {
        float* S1 = S1g6 + (size_t)i * GG * HH;
        float* S2 = S2g6 + (size_t)i * GG * HH;
        k_agg<<<NN / 16, 256, 0, stream>>>(ybuf, rowptr, col, dinv,
                                           conv_b + (size_t)i * HH, batch, aggb, S1, S2);
        k_finalize<<<GG, 128, 0, stream>>>(gptr, mean_scale + (size_t)i * HH,
                                           gamma + (size_t)i * HH, beta + (size_t)i * HH,
                                           S1, S2, c1t, c0t);
        k_mega<<<gmega, 64, 0, stream>>>(
            aggb, batch, c1t, c0t, w1b + (size_t)i * MM * HH, mlp_b1 + (size_t)i * MM,
            w2b + (size_t)i * HH * MM, mlp_b2 + (size_t)i * HH,
            cwb + (size_t)(i + 1 < LL ? i + 1 : 0) * HH * HH, dinv, hb, h_out, ybuf,
            i == LL - 1 ? 1 : 0, i < LL - 1 ? 1 : 0);
    }
}

// Round 7
// 1277.546 us; speedup vs baseline: 1.0682x; 1.0682x over previous
//
#include <hip/hip_runtime.h>

#define NN 100000
#define EE 1600000
#define HH 128
#define MM 256
#define LL 6
#define GG 512
#define SCAN_NB ((NN + 1023) / 1024)

typedef __attribute__((ext_vector_type(8))) short short8;
typedef __attribute__((ext_vector_type(4))) float floatx4;

__device__ __forceinline__ float swishf(float v) {
    // v * rcp(1+e^-v): rcp is ~1ulp f32, invisible vs bf16 quantization downstream.
    return v * __builtin_amdgcn_rcpf(1.0f + __expf(-v));
}

__device__ __forceinline__ unsigned short f2bf(float f) {
    unsigned u = __builtin_bit_cast(unsigned, f);
    unsigned r = u + 0x7FFFu + ((u >> 16) & 1u);
    return (unsigned short)(r >> 16);
}

__device__ __forceinline__ float bf2f(unsigned short u) {
    return __builtin_bit_cast(float, (unsigned)u << 16);
}

__device__ __forceinline__ float2 bf2f2(unsigned u) {
    float2 r;
    r.x = __builtin_bit_cast(float, u << 16);
    r.y = __builtin_bit_cast(float, u & 0xFFFF0000u);
    return r;
}

// RNE pack of two f32 -> one u32 of 2 bf16 (lo = a, hi = b). Bit-identical to f2bf.
__device__ __forceinline__ unsigned cvt2bf(float a, float b) {
    unsigned r;
    asm("v_cvt_pk_bf16_f32 %0, %1, %2" : "=v"(r) : "v"(a), "v"(b));
    return r;
}

__device__ __forceinline__ void unpack8(uint4 v, float* a) {
    float2 p0 = bf2f2(v.x), p1 = bf2f2(v.y), p2 = bf2f2(v.z), p3 = bf2f2(v.w);
    a[0] = p0.x; a[1] = p0.y; a[2] = p1.x; a[3] = p1.y;
    a[4] = p2.x; a[5] = p2.y; a[6] = p3.x; a[7] = p3.y;
}

__device__ __forceinline__ uint4 pack8(const float* o) {
    uint4 pk;
    pk.x = cvt2bf(o[0], o[1]);
    pk.y = cvt2bf(o[2], o[3]);
    pk.z = cvt2bf(o[4], o[5]);
    pk.w = cvt2bf(o[6], o[7]);
    return pk;
}

__device__ __forceinline__ uint2 pack4(const float* o) {
    uint2 pk;
    pk.x = cvt2bf(o[0], o[1]);
    pk.y = cvt2bf(o[2], o[3]);
    return pk;
}

// h[n,c] (row-major bf16) = z_embed[z[n],c] + x[:,1:]@ew^T + eb
__global__ void k_embed(const float* __restrict__ x, const float* __restrict__ z_embed,
                        const float* __restrict__ ew, const float* __restrict__ eb,
                        unsigned short* __restrict__ hb) {
    int idx = blockIdx.x * blockDim.x + threadIdx.x;
    if (idx >= NN * 32) return;
    int n = idx >> 5;
    int c0 = (idx & 31) << 2;
    const float* xr = x + (size_t)n * 4;
    int z = (int)xr[0];
    float x1 = xr[1], x2 = xr[2], x3 = xr[3];
    const float* ze = z_embed + (size_t)z * HH + c0;
    float o[4];
#pragma unroll
    for (int j = 0; j < 4; ++j) {
        int c = c0 + j;
        o[j] = ze[j] + x1 * ew[c * 3 + 0] + x2 * ew[c * 3 + 1] + x3 * ew[c * 3 + 2] + eb[c];
    }
    *(uint2*)(hb + (size_t)n * HH + c0) = pack4(o);
}

__global__ void k_f2bf3(const float* __restrict__ s1, unsigned short* __restrict__ d1, int n1,
                        const float* __restrict__ s2, unsigned short* __restrict__ d2, int n2,
                        const float* __restrict__ s3, unsigned short* __restrict__ d3, int n3) {
    int i = blockIdx.x * blockDim.x + threadIdx.x;
    if (i < n1) {
        d1[i] = f2bf(s1[i]);
    } else if (i < n1 + n2) {
        d2[i - n1] = f2bf(s2[i - n1]);
    } else if (i < n1 + n2 + n3) {
        d3[i - n1 - n2] = f2bf(s3[i - n1 - n2]);
    }
}

// Single-pass degree count: 1.6M atomics over 100K counters (~16/addr) is low
// contention; the old 8-partition scheme re-read the edge list 8x for nothing.
__global__ __launch_bounds__(256) void k_degree(const int* __restrict__ dst,
                                                int* __restrict__ deg) {
    for (int e = blockIdx.x * 256 + threadIdx.x; e < EE; e += gridDim.x * 256) {
        atomicAdd(&deg[dst[e]], 1);
    }
}

__global__ void k_dinv(const int* __restrict__ deg, float* __restrict__ dinv) {
    int n = blockIdx.x * blockDim.x + threadIdx.x;
    if (n < NN) dinv[n] = rsqrtf((float)(deg[n] + 1));
}

__global__ void k_scan1(const int* __restrict__ deg, int* __restrict__ bsum) {
    __shared__ int sd[256];
    int t = threadIdx.x;
    int base = blockIdx.x * 1024 + t * 4;
    int s = 0;
#pragma unroll
    for (int j = 0; j < 4; ++j) {
        int i = base + j;
        if (i < NN) s += deg[i];
    }
    sd[t] = s;
    __syncthreads();
    for (int off = 128; off > 0; off >>= 1) {
        if (t < off) sd[t] += sd[t + off];
        __syncthreads();
    }
    if (t == 0) bsum[blockIdx.x] = sd[0];
}

__global__ void k_scan2(const int* __restrict__ bsum, int* __restrict__ boff) {
    __shared__ int sd[128];
    int t = threadIdx.x;
    int v = (t < SCAN_NB) ? bsum[t] : 0;
    sd[t] = v;
    __syncthreads();
    for (int off = 1; off < 128; off <<= 1) {
        int u = (t >= off) ? sd[t - off] : 0;
        __syncthreads();
        sd[t] += u;
        __syncthreads();
    }
    boff[t] = sd[t] - v;  // exclusive
}

__global__ void k_scan3(const int* __restrict__ deg, const int* __restrict__ boff,
                        int* __restrict__ rowptr) {
    __shared__ int sd[256];
    int t = threadIdx.x;
    int base = blockIdx.x * 1024 + t * 4;
    int v[4];
    int s = 0;
#pragma unroll
    for (int j = 0; j < 4; ++j) {
        int i = base + j;
        v[j] = (i < NN) ? deg[i] : 0;
        s += v[j];
    }
    sd[t] = s;
    __syncthreads();
    for (int off = 1; off < 256; off <<= 1) {
        int u = (t >= off) ? sd[t - off] : 0;
        __syncthreads();
        sd[t] += u;
        __syncthreads();
    }
    int run = boff[blockIdx.x] + sd[t] - s;
#pragma unroll
    for (int j = 0; j < 4; ++j) {
        int i = base + j;
        if (i < NN) rowptr[i] = run;
        if (i == NN - 1) rowptr[NN] = run + v[j];
        run += v[j];
    }
}

// Single-pass CSR fill (order within a row is nondeterministic; summation order
// change is far below the bf16-dominated tolerance).
__global__ __launch_bounds__(256) void k_fill(const int* __restrict__ ei,
                                              const int* __restrict__ rowptr,
                                              int* __restrict__ cursor,
                                              int* __restrict__ col) {
    for (int e = blockIdx.x * 256 + threadIdx.x; e < EE; e += gridDim.x * 256) {
        int d = ei[EE + e];
        int p = atomicAdd(&cursor[d], 1);
        col[rowptr[d] + p] = ei[e];
    }
}

__global__ void k_gptr(const int* __restrict__ batch, int* __restrict__ gptr) {
    int n = blockIdx.x * blockDim.x + threadIdx.x;
    if (n >= NN) return;
    int b = batch[n];
    int pb = (n == 0) ? -1 : batch[n - 1];
    for (int g = pb + 1; g <= b; ++g) gptr[g] = n;
    if (n == NN - 1) {
        for (int g = b + 1; g <= GG; ++g) gptr[g] = NN;
    }
}

// Conv GEMM (layer 0 only): y = bf16((h @ Wc^T) * dinv[row]).
__global__ __launch_bounds__(256) void k_conv(const unsigned short* __restrict__ A,
                                              const unsigned short* __restrict__ B,
                                              const float* __restrict__ dinv,
                                              unsigned short* __restrict__ Cb) {
    __shared__ unsigned short Bs[128][HH + 8];
    const int tid = threadIdx.x;
    const int wave = tid >> 6;
    const int lane = tid & 63;
    const int quad = lane >> 4;
    const int l16 = lane & 15;
    const int wr = (wave & 1) << 6;
    const int wc = (wave >> 1) << 6;
    const int rowBase = blockIdx.x * 128;

    for (int i = tid; i < 128 * (HH / 8); i += 256) {
        int r = i / (HH / 8);
        int kk = (i % (HH / 8)) * 8;
        int rho = (r & 64) | ((r & 3) << 4) | ((r >> 2) & 15);
        *(uint4*)(&Bs[rho][kk]) = *(const uint4*)(B + (size_t)r * HH + kk);
    }

    floatx4 acc[4][4];
    const floatx4 zed = {0.f, 0.f, 0.f, 0.f};
#pragma unroll
    for (int i = 0; i < 4; ++i)
#pragma unroll
        for (int j = 0; j < 4; ++j) acc[i][j] = zed;

    int ar[4];
#pragma unroll
    for (int i = 0; i < 4; ++i) {
        int r = rowBase + wr + (i << 4) + l16;
        ar[i] = r < NN ? r : NN - 1;
    }

    __syncthreads();

#pragma unroll
    for (int ks = 0; ks < HH / 32; ++ks) {
        int k = (ks << 5) + (quad << 3);
        short8 a[4], b[4];
#pragma unroll
        for (int i = 0; i < 4; ++i) a[i] = *(const short8*)(A + (size_t)ar[i] * HH + k);
#pragma unroll
        for (int j = 0; j < 4; ++j) b[j] = *(const short8*)(&Bs[wc + (j << 4) + l16][k]);
#pragma unroll
        for (int i = 0; i < 4; ++i)
#pragma unroll
            for (int j = 0; j < 4; ++j)
                acc[i][j] =
                    __builtin_amdgcn_mfma_f32_16x16x32_bf16(a[i], b[j], acc[i][j], 0, 0, 0);
    }

    const int c0 = wc + (l16 << 2);
#pragma unroll
    for (int i = 0; i < 4; ++i) {
        int rb = rowBase + wr + (i << 4) + (quad << 2);
#pragma unroll
        for (int reg = 0; reg < 4; ++reg) {
            int r = rb + reg;
            if (r < NN) {
                float dv = dinv[r];
                float o[4];
#pragma unroll
                for (int j = 0; j < 4; ++j) o[j] = acc[i][j][reg] * dv;
                *(uint2*)(Cb + (size_t)r * HH + c0) = pack4(o);
            }
        }
    }
}

// Gather + fused per-graph stats. Wave = 4 consecutive nodes (block = 16; NN%16==0).
// Edge loop unrolled x4: 4 col reads + 4 256B row gathers in flight before
// consumption (quadruples MLP on the latency-exposed gather path).
__global__ __launch_bounds__(256) void k_agg(const unsigned short* __restrict__ y,
                                             const int* __restrict__ rowptr,
                                             const int* __restrict__ col,
                                             const float* __restrict__ dinv,
                                             const float* __restrict__ cb,
                                             const int* __restrict__ batch,
                                             unsigned short* __restrict__ agg,
                                             float* __restrict__ S1g,
                                             float* __restrict__ S2g) {
    __shared__ float s1s[4][128];
    __shared__ float s2s[4][128];
    __shared__ int sg[4];
    int w = threadIdx.x >> 6;
    int lane = threadIdx.x & 63;
    int grp = lane >> 4;
    int l16 = lane & 15;
    const uint4* yv = (const uint4*)y;
    const int dbase = blockIdx.x * 16 + w * 4;

    // conv bias is dispatch-invariant: hoist
    float cbv[8];
    {
        float4 c0 = *(const float4*)(cb + l16 * 8);
        float4 c1 = *(const float4*)(cb + l16 * 8 + 4);
        cbv[0] = c0.x; cbv[1] = c0.y; cbv[2] = c0.z; cbv[3] = c0.w;
        cbv[4] = c1.x; cbv[5] = c1.y; cbv[6] = c1.z; cbv[7] = c1.w;
    }

    float sA[8], sB[8];
#pragma unroll
    for (int j = 0; j < 8; ++j) { sA[j] = 0.f; sB[j] = 0.f; }
    int gcur = -1;

    for (int i = 0; i < 4; ++i) {
        int d = dbase + i;  // always < NN (NN % 16 == 0)
        float acc[8];
#pragma unroll
        for (int j = 0; j < 8; ++j) acc[j] = 0.f;
        if (grp == 0) {
            uint4 v = yv[(size_t)d * 16 + l16];
            unpack8(v, acc);
        }
        int beg = rowptr[d];
        int end = rowptr[d + 1];
        int e = beg + grp;
        for (; e + 12 < end; e += 16) {
            int s0 = col[e];
            int s1 = col[e + 4];
            int s2 = col[e + 8];
            int s3 = col[e + 12];
            uint4 v0 = yv[(size_t)s0 * 16 + l16];
            uint4 v1 = yv[(size_t)s1 * 16 + l16];
            uint4 v2 = yv[(size_t)s2 * 16 + l16];
            uint4 v3 = yv[(size_t)s3 * 16 + l16];
            float b0[8], b1[8], b2[8], b3[8];
            unpack8(v0, b0);
            unpack8(v1, b1);
            unpack8(v2, b2);
            unpack8(v3, b3);
#pragma unroll
            for (int k = 0; k < 8; ++k) acc[k] += (b0[k] + b1[k]) + (b2[k] + b3[k]);
        }
        for (; e < end; e += 4) {
            int s0 = col[e];
            uint4 v0 = yv[(size_t)s0 * 16 + l16];
            float b0[8];
            unpack8(v0, b0);
#pragma unroll
            for (int k = 0; k < 8; ++k) acc[k] += b0[k];
        }
#pragma unroll
        for (int j = 0; j < 8; ++j) {
            acc[j] += __shfl_xor(acc[j], 16, 64);
            acc[j] += __shfl_xor(acc[j], 32, 64);
        }
        if (grp == 0) {
            float dv = dinv[d];
            float o[8];
#pragma unroll
            for (int j = 0; j < 8; ++j) o[j] = acc[j] * dv + cbv[j];
            uint4 pk = pack8(o);
            *(uint4*)(agg + (size_t)d * HH + l16 * 8) = pk;
            float2 q0 = bf2f2(pk.x), q1 = bf2f2(pk.y), q2 = bf2f2(pk.z), q3 = bf2f2(pk.w);
            float orv[8] = {q0.x, q0.y, q1.x, q1.y, q2.x, q2.y, q3.x, q3.y};
            int g = batch[d];
            if (g != gcur) {
                if (gcur >= 0) {
#pragma unroll
                    for (int j = 0; j < 8; ++j) {
                        atomicAdd(&S1g[gcur * HH + l16 * 8 + j], sA[j]);
                        atomicAdd(&S2g[gcur * HH + l16 * 8 + j], sB[j]);
                    }
                }
                gcur = g;
#pragma unroll
                for (int j = 0; j < 8; ++j) {
                    sA[j] = orv[j];
                    sB[j] = orv[j] * orv[j];
                }
            } else {
#pragma unroll
                for (int j = 0; j < 8; ++j) {
                    sA[j] += orv[j];
                    sB[j] += orv[j] * orv[j];
                }
            }
        }
    }

    if (grp == 0) {
#pragma unroll
        for (int j = 0; j < 8; ++j) {
            s1s[w][l16 * 8 + j] = sA[j];
            s2s[w][l16 * 8 + j] = sB[j];
        }
        if (l16 == 0) sg[w] = gcur;
    }
    __syncthreads();
    if (threadIdx.x < 128) {
        int c = threadIdx.x;
        int g0 = sg[0], g1 = sg[1], g2 = sg[2], g3 = sg[3];
        if (g0 >= 0 && g0 == g1 && g0 == g2 && g0 == g3) {
            float a = (s1s[0][c] + s1s[1][c]) + (s1s[2][c] + s1s[3][c]);
            float b = (s2s[0][c] + s2s[1][c]) + (s2s[2][c] + s2s[3][c]);
            atomicAdd(&S1g[g0 * HH + c], a);
            atomicAdd(&S2g[g0 * HH + c], b);
        } else {
            int gs[4] = {g0, g1, g2, g3};
#pragma unroll
            for (int ww = 0; ww < 4; ++ww) {
                if (gs[ww] >= 0) {
                    atomicAdd(&S1g[gs[ww] * HH + c], s1s[ww][c]);
                    atomicAdd(&S2g[gs[ww] * HH + c], s2s[ww][c]);
                }
            }
        }
    }
}

// finalize: c1 = gamma*rstd, c0 = beta - c1*ms*mean (per-layer S buffers; no re-zero)
__global__ __launch_bounds__(128) void k_finalize(const int* __restrict__ gptr,
                                                  const float* __restrict__ ms,
                                                  const float* __restrict__ gamma,
                                                  const float* __restrict__ beta,
                                                  const float* __restrict__ S1g,
                                                  const float* __restrict__ S2g,
                                                  float* __restrict__ c1,
                                                  float* __restrict__ c0) {
    int g = blockIdx.x;
    int c = threadIdx.x;
    int cnt = gptr[g + 1] - gptr[g];
    float inv = 1.0f / (float)(cnt > 0 ? cnt : 1);
    float S1 = S1g[g * HH + c];
    float S2 = S2g[g * HH + c];
    float m = S1 * inv;
    float msc = ms[c];
    float var = S2 * inv - msc * (2.0f - msc) * m * m;
    float rstd = rsqrtf(var + 1e-5f);
    float c1v = gamma[c] * rstd;
    c1[g * HH + c] = c1v;
    c0[g * HH + c] = beta[c] - c1v * msc * m;
}

// Mega layer kernel (r4-proven variant, 90.6 us): 256 threads, 64 rows, 4 waves,
// LDS 34.8 KB (4 blocks/CU). Residual hb read stays ADJACENT to its write
// (r3 lesson: early prefetch doubles FETCH+WRITE via evict + write-allocate).
// Phase 0: ha = swish(c1*agg + c0) -> LDS ha_s[64][136].
// Phase A_h/B_h: t halves through ts[64][136], persistent acc2.
// Epilogue: h' -> hb + ha_s (doConv) or h_out f32 (last layer).
// Phase C (doConv): y_next = bf16((h'@Wc^T)*dinv).
__global__ __launch_bounds__(256, 4) void k_mega(const unsigned short* __restrict__ agg,
                                                 const int* __restrict__ batch,
                                                 const float* __restrict__ c1,
                                                 const float* __restrict__ c0,
                                                 const unsigned short* __restrict__ W1,
                                                 const float* __restrict__ b1,
                                                 const unsigned short* __restrict__ W2,
                                                 const float* __restrict__ b2,
                                                 const unsigned short* __restrict__ Wc,
                                                 const float* __restrict__ dinv,
                                                 unsigned short* __restrict__ hb,
                                                 float* __restrict__ h_out,
                                                 unsigned short* __restrict__ y_out,
                                                 int writeF, int doConv) {
    __shared__ unsigned short ha_s[64 * 136];  // ha, then h' (pitch 136)
    __shared__ unsigned short ts[64 * 136];    // one 128-col half of t (pitch 136)
    const int tid = threadIdx.x;
    const int wave = tid >> 6;
    const int lane = tid & 63;
    const int quad = lane >> 4;
    const int l16 = lane & 15;
    const int rowBase = blockIdx.x * 64;
    const floatx4 zed = {0.f, 0.f, 0.f, 0.f};

    const int wrb = (wave & 1) << 5;   // 0/32
    const int wcb = (wave >> 1) << 6;  // 0/64
    const int co = wcb + (l16 << 2);

    // ---- phase 0: normswish -> ha_s ----
    {
        int lr = tid >> 2;           // 0..63
        int coff = (tid & 3) << 5;   // 0,32,64,96
        int r = rowBase + lr;
        if (r >= NN) r = NN - 1;
        int g = batch[r];
        const float* c1p = c1 + g * HH + coff;
        const float* c0p = c0 + g * HH + coff;
#pragma unroll
        for (int q = 0; q < 4; ++q) {
            uint4 raw = *(const uint4*)(agg + (size_t)r * HH + coff + (q << 3));
            float v[8];
            unpack8(raw, v);
            float4 ca = *(const float4*)(c1p + (q << 3));
            float4 cb4 = *(const float4*)(c1p + (q << 3) + 4);
            float4 da = *(const float4*)(c0p + (q << 3));
            float4 db = *(const float4*)(c0p + (q << 3) + 4);
            float cc1[8] = {ca.x, ca.y, ca.z, ca.w, cb4.x, cb4.y, cb4.z, cb4.w};
            float cc0[8] = {da.x, da.y, da.z, da.w, db.x, db.y, db.z, db.w};
            float o[8];
#pragma unroll
            for (int j = 0; j < 8; ++j) o[j] = swishf(cc1[j] * v[j] + cc0[j]);
            *(uint4*)(&ha_s[lr * 136 + coff + (q << 3)]) = pack8(o);
        }
    }
    __syncthreads();

    {
        floatx4 acc2[2][4];
#pragma unroll
        for (int i = 0; i < 2; ++i)
#pragma unroll
            for (int j = 0; j < 4; ++j) acc2[i][j] = zed;

#pragma unroll
        for (int h = 0; h < 2; ++h) {
            // ---- phase A half h: t[:, 128h+32w .. +32) = swish(ha @ W1^T + b1) ----
            floatx4 acc1[4][2];
#pragma unroll
            for (int i = 0; i < 4; ++i)
#pragma unroll
                for (int j = 0; j < 2; ++j) acc1[i][j] = zed;
            const int tcol = (wave << 5) + (l16 << 1);  // local col in half, 0..127
#pragma unroll
            for (int ks = 0; ks < 4; ++ks) {
                int k = (ks << 5) + (quad << 3);
                short8 a[4], b[2];
#pragma unroll
                for (int i = 0; i < 4; ++i)
                    a[i] = *(const short8*)(&ha_s[((i << 4) + l16) * 136 + k]);
#pragma unroll
                for (int j = 0; j < 2; ++j)
                    b[j] = *(const short8*)(W1 + (size_t)((h << 7) + tcol + j) * HH + k);
#pragma unroll
                for (int i = 0; i < 4; ++i)
#pragma unroll
                    for (int j = 0; j < 2; ++j)
                        acc1[i][j] = __builtin_amdgcn_mfma_f32_16x16x32_bf16(a[i], b[j],
                                                                             acc1[i][j], 0, 0, 0);
            }
            float2 bv = *(const float2*)(b1 + (h << 7) + tcol);
#pragma unroll
            for (int i = 0; i < 4; ++i) {
#pragma unroll
                for (int reg = 0; reg < 4; ++reg) {
                    int lr = (i << 4) + (quad << 2) + reg;
                    float o0 = swishf(acc1[i][0][reg] + bv.x);
                    float o1 = swishf(acc1[i][1][reg] + bv.y);
                    *(unsigned*)(&ts[lr * 136 + tcol]) = cvt2bf(o0, o1);
                }
            }
            __syncthreads();

            // ---- phase B half h: acc2 += t_h @ W2[:, 128h:+128]^T ----
#pragma unroll
            for (int ks = 0; ks < 4; ++ks) {
                int k = (ks << 5) + (quad << 3);
                short8 a[2], b[4];
#pragma unroll
                for (int i = 0; i < 2; ++i)
                    a[i] = *(const short8*)(&ts[(wrb + (i << 4) + l16) * 136 + k]);
#pragma unroll
                for (int j = 0; j < 4; ++j)
                    b[j] = *(const short8*)(W2 + (size_t)(wcb + (l16 << 2) + j) * MM +
                                            (h << 7) + k);
#pragma unroll
                for (int i = 0; i < 2; ++i)
#pragma unroll
                    for (int j = 0; j < 4; ++j)
                        acc2[i][j] = __builtin_amdgcn_mfma_f32_16x16x32_bf16(a[i], b[j],
                                                                             acc2[i][j], 0, 0, 0);
            }
            if (h == 0) __syncthreads();  // before next half overwrites ts
        }

        // ---- epilogue: h' = swish(acc2 + b2) + res ----
        float4 b4 = *(const float4*)(b2 + co);
        float bv[4] = {b4.x, b4.y, b4.z, b4.w};
#pragma unroll
        for (int i = 0; i < 2; ++i) {
#pragma unroll
            for (int reg = 0; reg < 4; ++reg) {
                int lr = wrb + (i << 4) + (quad << 2) + reg;
                int r = rowBase + lr;
                if (r < NN) {
                    uint2 rv = *(const uint2*)(hb + (size_t)r * HH + co);
                    float2 r01 = bf2f2(rv.x), r23 = bf2f2(rv.y);
                    float o[4];
                    o[0] = swishf(acc2[i][0][reg] + bv[0]) + r01.x;
                    o[1] = swishf(acc2[i][1][reg] + bv[1]) + r01.y;
                    o[2] = swishf(acc2[i][2][reg] + bv[2]) + r23.x;
                    o[3] = swishf(acc2[i][3][reg] + bv[3]) + r23.y;
                    if (doConv) {
                        uint2 pk = pack4(o);
                        *(uint2*)(hb + (size_t)r * HH + co) = pk;
                        *(uint2*)(&ha_s[lr * 136 + co]) = pk;
                    } else {
                        *(float4*)(h_out + (size_t)r * HH + co) =
                            make_float4(o[0], o[1], o[2], o[3]);
                    }
                } else if (doConv) {
                    *(uint2*)(&ha_s[lr * 136 + co]) = make_uint2(0u, 0u);
                }
            }
        }
    }

    // ---- phase C: y_next = bf16((h' @ Wc^T) * dinv) ----
    if (doConv) {
        __syncthreads();
        floatx4 acc3[2][4];
#pragma unroll
        for (int i = 0; i < 2; ++i)
#pragma unroll
            for (int j = 0; j < 4; ++j) acc3[i][j] = zed;
#pragma unroll
        for (int ks = 0; ks < 4; ++ks) {
            int k = (ks << 5) + (quad << 3);
            short8 a[2], b[4];
#pragma unroll
            for (int i = 0; i < 2; ++i)
                a[i] = *(const short8*)(&ha_s[(wrb + (i << 4) + l16) * 136 + k]);
#pragma unroll
            for (int j = 0; j < 4; ++j)
                b[j] = *(const short8*)(Wc + (size_t)(wcb + (l16 << 2) + j) * HH + k);
#pragma unroll
            for (int i = 0; i < 2; ++i)
#pragma unroll
                for (int j = 0; j < 4; ++j)
                    acc3[i][j] =
                        __builtin_amdgcn_mfma_f32_16x16x32_bf16(a[i], b[j], acc3[i][j], 0, 0, 0);
        }
#pragma unroll
        for (int i = 0; i < 2; ++i) {
#pragma unroll
            for (int reg = 0; reg < 4; ++reg) {
                int r = rowBase + wrb + (i << 4) + (quad << 2) + reg;
                if (r < NN) {
                    float dv = dinv[r];
                    float o[4];
#pragma unroll
                    for (int j = 0; j < 4; ++j) o[j] = acc3[i][j][reg] * dv;
                    *(uint2*)(y_out + (size_t)r * HH + co) = pack4(o);
                }
            }
        }
    }
}

extern "C" void kernel_launch(void* const* d_in, const int* in_sizes, int n_in,
                              void* d_out, int out_size, void* d_ws, size_t ws_size,
                              hipStream_t stream) {
    const float* x = (const float*)d_in[0];
    const int* ei = (const int*)d_in[1];
    const int* batch = (const int*)d_in[2];
    const float* z_embed = (const float*)d_in[3];
    const float* extra_w = (const float*)d_in[4];
    const float* extra_b = (const float*)d_in[5];
    const float* conv_w = (const float*)d_in[6];
    const float* conv_b = (const float*)d_in[7];
    const float* gamma = (const float*)d_in[8];
    const float* beta = (const float*)d_in[9];
    const float* mean_scale = (const float*)d_in[10];
    const float* mlp_w1 = (const float*)d_in[11];
    const float* mlp_b1 = (const float*)d_in[12];
    const float* mlp_w2 = (const float*)d_in[13];
    const float* mlp_b2 = (const float*)d_in[14];
    float* h_out = (float*)d_out;

    char* wsB = (char*)d_ws;
    size_t off = 0;
    auto alloc = [&](size_t bytes) -> void* {
        void* p = (void*)(wsB + off);
        off = (off + bytes + 255) & ~(size_t)255;
        return p;
    };
    float* dinv = (float*)alloc((size_t)NN * 4);
    int* deg = (int*)alloc((size_t)NN * 4);
    int* cursor = (int*)alloc((size_t)NN * 4);
    int* rowptr = (int*)alloc((size_t)(NN + 1) * 4);
    int* bsum = (int*)alloc(128 * 4);
    int* boff = (int*)alloc(128 * 4);
    int* col = (int*)alloc((size_t)EE * 4);
    int* gptr = (int*)alloc((size_t)(GG + 1) * 4);
    float* c1t = (float*)alloc((size_t)GG * HH * 4);
    float* c0t = (float*)alloc((size_t)GG * HH * 4);
    float* S1g6 = (float*)alloc((size_t)LL * GG * HH * 4);  // per-layer stats, zeroed once
    float* S2g6 = (float*)alloc((size_t)LL * GG * HH * 4);
    unsigned short* wb =
        (unsigned short*)alloc((size_t)(LL * (HH * HH + MM * HH + HH * MM)) * 2);
    unsigned short* cwb = wb;
    unsigned short* w1b = wb + (size_t)LL * HH * HH;
    unsigned short* w2b = w1b + (size_t)LL * MM * HH;
    unsigned short* hb = (unsigned short*)alloc((size_t)NN * HH * 2);    // bf16 residual
    unsigned short* ybuf = (unsigned short*)alloc((size_t)NN * HH * 2);  // y (conv out)
    unsigned short* aggb = (unsigned short*)alloc((size_t)NN * HH * 2);  // agg bf16

    hipMemsetAsync(deg, 0, (size_t)NN * 4, stream);
    hipMemsetAsync(cursor, 0, (size_t)NN * 4, stream);
    hipMemsetAsync(S1g6, 0, (size_t)LL * GG * HH * 4, stream);
    hipMemsetAsync(S2g6, 0, (size_t)LL * GG * HH * 4, stream);

    k_embed<<<(NN * 32 + 255) / 256, 256, 0, stream>>>(x, z_embed, extra_w, extra_b, hb);
    {
        int n1 = LL * HH * HH, n2 = LL * MM * HH, n3 = LL * HH * MM;
        int nt = n1 + n2 + n3;
        k_f2bf3<<<(nt + 255) / 256, 256, 0, stream>>>(conv_w, cwb, n1, mlp_w1, w1b, n2,
                                                      mlp_w2, w2b, n3);
    }
    k_degree<<<2048, 256, 0, stream>>>(ei + EE, deg);
    k_dinv<<<(NN + 255) / 256, 256, 0, stream>>>(deg, dinv);
    k_scan1<<<SCAN_NB, 256, 0, stream>>>(deg, bsum);
    k_scan2<<<1, 128, 0, stream>>>(bsum, boff);
    k_scan3<<<SCAN_NB, 256, 0, stream>>>(deg, boff, rowptr);
    k_fill<<<2048, 256, 0, stream>>>(ei, rowptr, cursor, col);
    k_gptr<<<(NN + 255) / 256, 256, 0, stream>>>(batch, gptr);

    int gconv = (NN + 127) / 128;
    int gmega = (NN + 63) / 64;
    k_conv<<<gconv, 256, 0, stream>>>(hb, cwb, dinv, ybuf);
    for (int i = 0; i < LL; ++i) {
        float* S1 = S1g6 + (size_t)i * GG * HH;
        float* S2 = S2g6 + (size_t)i * GG * HH;
        k_agg<<<NN / 16, 256, 0, stream>>>(ybuf, rowptr, col, dinv,
                                           conv_b + (size_t)i * HH, batch, aggb, S1, S2);
        k_finalize<<<GG, 128, 0, stream>>>(gptr, mean_scale + (size_t)i * HH,
                                           gamma + (size_t)i * HH, beta + (size_t)i * HH,
                                           S1, S2, c1t, c0t);
        k_mega<<<gmega, 256, 0, stream>>>(
            aggb, batch, c1t, c0t, w1b + (size_t)i * MM * HH, mlp_b1 + (size_t)i * MM,
            w2b + (size_t)i * HH * MM, mlp_b2 + (size_t)i * HH,
            cwb + (size_t)(i + 1 < LL ? i + 1 : 0) * HH * HH, dinv, hb, h_out, ybuf,
            i == LL - 1 ? 1 : 0, i < LL - 1 ? 1 : 0);
    }
}

// Round 8
// 1221.213 us; speedup vs baseline: 1.1175x; 1.0461x over previous
//
#include <hip/hip_runtime.h>

#define NN 100000
#define EE 1600000
#define HH 128
#define MM 256
#define LL 6
#define GG 512
#define SCAN_NB ((NN + 1023) / 1024)

typedef __attribute__((ext_vector_type(8))) short short8;
typedef __attribute__((ext_vector_type(4))) float floatx4;

__device__ __forceinline__ float swishf(float v) {
    // v * rcp(1+e^-v): rcp is ~1ulp f32, invisible vs bf16 quantization downstream.
    return v * __builtin_amdgcn_rcpf(1.0f + __expf(-v));
}

__device__ __forceinline__ unsigned short f2bf(float f) {
    unsigned u = __builtin_bit_cast(unsigned, f);
    unsigned r = u + 0x7FFFu + ((u >> 16) & 1u);
    return (unsigned short)(r >> 16);
}

__device__ __forceinline__ float bf2f(unsigned short u) {
    return __builtin_bit_cast(float, (unsigned)u << 16);
}

__device__ __forceinline__ float2 bf2f2(unsigned u) {
    float2 r;
    r.x = __builtin_bit_cast(float, u << 16);
    r.y = __builtin_bit_cast(float, u & 0xFFFF0000u);
    return r;
}

// RNE pack of two f32 -> one u32 of 2 bf16 (lo = a, hi = b). Bit-identical to f2bf.
__device__ __forceinline__ unsigned cvt2bf(float a, float b) {
    unsigned r;
    asm("v_cvt_pk_bf16_f32 %0, %1, %2" : "=v"(r) : "v"(a), "v"(b));
    return r;
}

__device__ __forceinline__ void unpack8(uint4 v, float* a) {
    float2 p0 = bf2f2(v.x), p1 = bf2f2(v.y), p2 = bf2f2(v.z), p3 = bf2f2(v.w);
    a[0] = p0.x; a[1] = p0.y; a[2] = p1.x; a[3] = p1.y;
    a[4] = p2.x; a[5] = p2.y; a[6] = p3.x; a[7] = p3.y;
}

__device__ __forceinline__ uint4 pack8(const float* o) {
    uint4 pk;
    pk.x = cvt2bf(o[0], o[1]);
    pk.y = cvt2bf(o[2], o[3]);
    pk.z = cvt2bf(o[4], o[5]);
    pk.w = cvt2bf(o[6], o[7]);
    return pk;
}

__device__ __forceinline__ uint2 pack4(const float* o) {
    uint2 pk;
    pk.x = cvt2bf(o[0], o[1]);
    pk.y = cvt2bf(o[2], o[3]);
    return pk;
}

// h[n,c] (row-major bf16) = z_embed[z[n],c] + x[:,1:]@ew^T + eb
__global__ void k_embed(const float* __restrict__ x, const float* __restrict__ z_embed,
                        const float* __restrict__ ew, const float* __restrict__ eb,
                        unsigned short* __restrict__ hb) {
    int idx = blockIdx.x * blockDim.x + threadIdx.x;
    if (idx >= NN * 32) return;
    int n = idx >> 5;
    int c0 = (idx & 31) << 2;
    const float* xr = x + (size_t)n * 4;
    int z = (int)xr[0];
    float x1 = xr[1], x2 = xr[2], x3 = xr[3];
    const float* ze = z_embed + (size_t)z * HH + c0;
    float o[4];
#pragma unroll
    for (int j = 0; j < 4; ++j) {
        int c = c0 + j;
        o[j] = ze[j] + x1 * ew[c * 3 + 0] + x2 * ew[c * 3 + 1] + x3 * ew[c * 3 + 2] + eb[c];
    }
    *(uint2*)(hb + (size_t)n * HH + c0) = pack4(o);
}

__global__ void k_f2bf3(const float* __restrict__ s1, unsigned short* __restrict__ d1, int n1,
                        const float* __restrict__ s2, unsigned short* __restrict__ d2, int n2,
                        const float* __restrict__ s3, unsigned short* __restrict__ d3, int n3) {
    int i = blockIdx.x * blockDim.x + threadIdx.x;
    if (i < n1) {
        d1[i] = f2bf(s1[i]);
    } else if (i < n1 + n2) {
        d2[i - n1] = f2bf(s2[i - n1]);
    } else if (i < n1 + n2 + n3) {
        d3[i - n1 - n2] = f2bf(s3[i - n1 - n2]);
    }
}

// 8-partition degree count (r7 lesson: partition = blockIdx&7 aligns with the
// round-robin block->XCD mapping, so each XCD's L2 only sees 1/8 of the counter
// array; the 8x streaming re-reads are cheap insurance vs scattered-write cost).
__global__ __launch_bounds__(256) void k_degree_p(const int* __restrict__ dst,
                                                  int* __restrict__ deg) {
    int part = blockIdx.x & 7;
    int blk = blockIdx.x >> 3;
    int nb = gridDim.x >> 3;
    int lo = (int)((long long)part * NN / 8);
    int hi = (int)((long long)(part + 1) * NN / 8);
    for (int e = blk * 256 + threadIdx.x; e < EE; e += nb * 256) {
        int d = dst[e];
        if (d >= lo && d < hi) atomicAdd(&deg[d], 1);
    }
}

// scan1 with fused dinv (both read deg; saves a dispatch)
__global__ void k_scan1(const int* __restrict__ deg, int* __restrict__ bsum,
                        float* __restrict__ dinv) {
    __shared__ int sd[256];
    int t = threadIdx.x;
    int base = blockIdx.x * 1024 + t * 4;
    int s = 0;
#pragma unroll
    for (int j = 0; j < 4; ++j) {
        int i = base + j;
        if (i < NN) {
            int dg = deg[i];
            s += dg;
            dinv[i] = rsqrtf((float)(dg + 1));
        }
    }
    sd[t] = s;
    __syncthreads();
    for (int off = 128; off > 0; off >>= 1) {
        if (t < off) sd[t] += sd[t + off];
        __syncthreads();
    }
    if (t == 0) bsum[blockIdx.x] = sd[0];
}

__global__ void k_scan2(const int* __restrict__ bsum, int* __restrict__ boff) {
    __shared__ int sd[128];
    int t = threadIdx.x;
    int v = (t < SCAN_NB) ? bsum[t] : 0;
    sd[t] = v;
    __syncthreads();
    for (int off = 1; off < 128; off <<= 1) {
        int u = (t >= off) ? sd[t - off] : 0;
        __syncthreads();
        sd[t] += u;
        __syncthreads();
    }
    boff[t] = sd[t] - v;  // exclusive
}

__global__ void k_scan3(const int* __restrict__ deg, const int* __restrict__ boff,
                        int* __restrict__ rowptr) {
    __shared__ int sd[256];
    int t = threadIdx.x;
    int base = blockIdx.x * 1024 + t * 4;
    int v[4];
    int s = 0;
#pragma unroll
    for (int j = 0; j < 4; ++j) {
        int i = base + j;
        v[j] = (i < NN) ? deg[i] : 0;
        s += v[j];
    }
    sd[t] = s;
    __syncthreads();
    for (int off = 1; off < 256; off <<= 1) {
        int u = (t >= off) ? sd[t - off] : 0;
        __syncthreads();
        sd[t] += u;
        __syncthreads();
    }
    int run = boff[blockIdx.x] + sd[t] - s;
#pragma unroll
    for (int j = 0; j < 4; ++j) {
        int i = base + j;
        if (i < NN) rowptr[i] = run;
        if (i == NN - 1) rowptr[NN] = run + v[j];
        run += v[j];
    }
}

// 8-partition CSR fill (write-locality machinery; see k_degree_p comment /
// r7 lesson: single-pass scattered 4B col writes cost 108 MB of writeback).
__global__ __launch_bounds__(256) void k_fill_p(const int* __restrict__ ei,
                                                const int* __restrict__ rowptr,
                                                int* __restrict__ cursor,
                                                int* __restrict__ col) {
    int part = blockIdx.x & 7;
    int blk = blockIdx.x >> 3;
    int nb = gridDim.x >> 3;
    int lo = (int)((long long)part * NN / 8);
    int hi = (int)((long long)(part + 1) * NN / 8);
    for (int e = blk * 256 + threadIdx.x; e < EE; e += nb * 256) {
        int d = ei[EE + e];
        if (d >= lo && d < hi) {
            int p = atomicAdd(&cursor[d], 1);
            col[rowptr[d] + p] = ei[e];
        }
    }
}

__global__ void k_gptr(const int* __restrict__ batch, int* __restrict__ gptr) {
    int n = blockIdx.x * blockDim.x + threadIdx.x;
    if (n >= NN) return;
    int b = batch[n];
    int pb = (n == 0) ? -1 : batch[n - 1];
    for (int g = pb + 1; g <= b; ++g) gptr[g] = n;
    if (n == NN - 1) {
        for (int g = b + 1; g <= GG; ++g) gptr[g] = NN;
    }
}

// Conv GEMM (layer 0 only): y = bf16((h @ Wc^T) * dinv[row]).
__global__ __launch_bounds__(256) void k_conv(const unsigned short* __restrict__ A,
                                              const unsigned short* __restrict__ B,
                                              const float* __restrict__ dinv,
                                              unsigned short* __restrict__ Cb) {
    __shared__ unsigned short Bs[128][HH + 8];
    const int tid = threadIdx.x;
    const int wave = tid >> 6;
    const int lane = tid & 63;
    const int quad = lane >> 4;
    const int l16 = lane & 15;
    const int wr = (wave & 1) << 6;
    const int wc = (wave >> 1) << 6;
    const int rowBase = blockIdx.x * 128;

    for (int i = tid; i < 128 * (HH / 8); i += 256) {
        int r = i / (HH / 8);
        int kk = (i % (HH / 8)) * 8;
        int rho = (r & 64) | ((r & 3) << 4) | ((r >> 2) & 15);
        *(uint4*)(&Bs[rho][kk]) = *(const uint4*)(B + (size_t)r * HH + kk);
    }

    floatx4 acc[4][4];
    const floatx4 zed = {0.f, 0.f, 0.f, 0.f};
#pragma unroll
    for (int i = 0; i < 4; ++i)
#pragma unroll
        for (int j = 0; j < 4; ++j) acc[i][j] = zed;

    int ar[4];
#pragma unroll
    for (int i = 0; i < 4; ++i) {
        int r = rowBase + wr + (i << 4) + l16;
        ar[i] = r < NN ? r : NN - 1;
    }

    __syncthreads();

#pragma unroll
    for (int ks = 0; ks < HH / 32; ++ks) {
        int k = (ks << 5) + (quad << 3);
        short8 a[4], b[4];
#pragma unroll
        for (int i = 0; i < 4; ++i) a[i] = *(const short8*)(A + (size_t)ar[i] * HH + k);
#pragma unroll
        for (int j = 0; j < 4; ++j) b[j] = *(const short8*)(&Bs[wc + (j << 4) + l16][k]);
#pragma unroll
        for (int i = 0; i < 4; ++i)
#pragma unroll
            for (int j = 0; j < 4; ++j)
                acc[i][j] =
                    __builtin_amdgcn_mfma_f32_16x16x32_bf16(a[i], b[j], acc[i][j], 0, 0, 0);
    }

    const int c0 = wc + (l16 << 2);
#pragma unroll
    for (int i = 0; i < 4; ++i) {
        int rb = rowBase + wr + (i << 4) + (quad << 2);
#pragma unroll
        for (int reg = 0; reg < 4; ++reg) {
            int r = rb + reg;
            if (r < NN) {
                float dv = dinv[r];
                float o[4];
#pragma unroll
                for (int j = 0; j < 4; ++j) o[j] = acc[i][j][reg] * dv;
                *(uint2*)(Cb + (size_t)r * HH + c0) = pack4(o);
            }
        }
    }
}

// Gather + fused per-graph stats. Wave = 4 consecutive nodes (block = 16; NN%16==0).
// Edge loop unrolled x2 (r4-proven; x4 halves occupancy for zero gain — the
// gather sits at the ~2.6-2.8 TB/s random-256B ceiling regardless).
__global__ __launch_bounds__(256) void k_agg(const unsigned short* __restrict__ y,
                                             const int* __restrict__ rowptr,
                                             const int* __restrict__ col,
                                             const float* __restrict__ dinv,
                                             const float* __restrict__ cb,
                                             const int* __restrict__ batch,
                                             unsigned short* __restrict__ agg,
                                             float* __restrict__ S1g,
                                             float* __restrict__ S2g) {
    __shared__ float s1s[4][128];
    __shared__ float s2s[4][128];
    __shared__ int sg[4];
    int w = threadIdx.x >> 6;
    int lane = threadIdx.x & 63;
    int grp = lane >> 4;
    int l16 = lane & 15;
    const uint4* yv = (const uint4*)y;
    const int dbase = blockIdx.x * 16 + w * 4;

    // conv bias is dispatch-invariant: hoist
    float cbv[8];
    {
        float4 c0 = *(const float4*)(cb + l16 * 8);
        float4 c1 = *(const float4*)(cb + l16 * 8 + 4);
        cbv[0] = c0.x; cbv[1] = c0.y; cbv[2] = c0.z; cbv[3] = c0.w;
        cbv[4] = c1.x; cbv[5] = c1.y; cbv[6] = c1.z; cbv[7] = c1.w;
    }

    float sA[8], sB[8];
#pragma unroll
    for (int j = 0; j < 8; ++j) { sA[j] = 0.f; sB[j] = 0.f; }
    int gcur = -1;

    for (int i = 0; i < 4; ++i) {
        int d = dbase + i;  // always < NN (NN % 16 == 0)
        float acc[8];
#pragma unroll
        for (int j = 0; j < 8; ++j) acc[j] = 0.f;
        if (grp == 0) {
            uint4 v = yv[(size_t)d * 16 + l16];
            unpack8(v, acc);
        }
        int beg = rowptr[d];
        int end = rowptr[d + 1];
        int e = beg + grp;
        for (; e + 4 < end; e += 8) {
            int s0 = col[e];
            int s1 = col[e + 4];
            uint4 v0 = yv[(size_t)s0 * 16 + l16];
            uint4 v1 = yv[(size_t)s1 * 16 + l16];
            float b0[8], b1[8];
            unpack8(v0, b0);
            unpack8(v1, b1);
#pragma unroll
            for (int k = 0; k < 8; ++k) acc[k] += (b0[k] + b1[k]);
        }
        if (e < end) {
            int s0 = col[e];
            uint4 v0 = yv[(size_t)s0 * 16 + l16];
            float b0[8];
            unpack8(v0, b0);
#pragma unroll
            for (int k = 0; k < 8; ++k) acc[k] += b0[k];
        }
#pragma unroll
        for (int j = 0; j < 8; ++j) {
            acc[j] += __shfl_xor(acc[j], 16, 64);
            acc[j] += __shfl_xor(acc[j], 32, 64);
        }
        if (grp == 0) {
            float dv = dinv[d];
            float o[8];
#pragma unroll
            for (int j = 0; j < 8; ++j) o[j] = acc[j] * dv + cbv[j];
            uint4 pk = pack8(o);
            *(uint4*)(agg + (size_t)d * HH + l16 * 8) = pk;
            float2 q0 = bf2f2(pk.x), q1 = bf2f2(pk.y), q2 = bf2f2(pk.z), q3 = bf2f2(pk.w);
            float orv[8] = {q0.x, q0.y, q1.x, q1.y, q2.x, q2.y, q3.x, q3.y};
            int g = batch[d];
            if (g != gcur) {
                if (gcur >= 0) {
#pragma unroll
                    for (int j = 0; j < 8; ++j) {
                        atomicAdd(&S1g[gcur * HH + l16 * 8 + j], sA[j]);
                        atomicAdd(&S2g[gcur * HH + l16 * 8 + j], sB[j]);
                    }
                }
                gcur = g;
#pragma unroll
                for (int j = 0; j < 8; ++j) {
                    sA[j] = orv[j];
                    sB[j] = orv[j] * orv[j];
                }
            } else {
#pragma unroll
                for (int j = 0; j < 8; ++j) {
                    sA[j] += orv[j];
                    sB[j] += orv[j] * orv[j];
                }
            }
        }
    }

    if (grp == 0) {
#pragma unroll
        for (int j = 0; j < 8; ++j) {
            s1s[w][l16 * 8 + j] = sA[j];
            s2s[w][l16 * 8 + j] = sB[j];
        }
        if (l16 == 0) sg[w] = gcur;
    }
    __syncthreads();
    if (threadIdx.x < 128) {
        int c = threadIdx.x;
        int g0 = sg[0], g1 = sg[1], g2 = sg[2], g3 = sg[3];
        if (g0 >= 0 && g0 == g1 && g0 == g2 && g0 == g3) {
            float a = (s1s[0][c] + s1s[1][c]) + (s1s[2][c] + s1s[3][c]);
            float b = (s2s[0][c] + s2s[1][c]) + (s2s[2][c] + s2s[3][c]);
            atomicAdd(&S1g[g0 * HH + c], a);
            atomicAdd(&S2g[g0 * HH + c], b);
        } else {
            int gs[4] = {g0, g1, g2, g3};
#pragma unroll
            for (int ww = 0; ww < 4; ++ww) {
                if (gs[ww] >= 0) {
                    atomicAdd(&S1g[gs[ww] * HH + c], s1s[ww][c]);
                    atomicAdd(&S2g[gs[ww] * HH + c], s2s[ww][c]);
                }
            }
        }
    }
}

// finalize: c1 = gamma*rstd, c0 = beta - c1*ms*mean (per-layer S buffers; no re-zero)
__global__ __launch_bounds__(128) void k_finalize(const int* __restrict__ gptr,
                                                  const float* __restrict__ ms,
                                                  const float* __restrict__ gamma,
                                                  const float* __restrict__ beta,
                                                  const float* __restrict__ S1g,
                                                  const float* __restrict__ S2g,
                                                  float* __restrict__ c1,
                                                  float* __restrict__ c0) {
    int g = blockIdx.x;
    int c = threadIdx.x;
    int cnt = gptr[g + 1] - gptr[g];
    float inv = 1.0f / (float)(cnt > 0 ? cnt : 1);
    float S1 = S1g[g * HH + c];
    float S2 = S2g[g * HH + c];
    float m = S1 * inv;
    float msc = ms[c];
    float var = S2 * inv - msc * (2.0f - msc) * m * m;
    float rstd = rsqrtf(var + 1e-5f);
    float c1v = gamma[c] * rstd;
    c1[g * HH + c] = c1v;
    c0[g * HH + c] = beta[c] - c1v * msc * m;
}

// Mega layer kernel (r4-proven variant, 90.6 us): 256 threads, 64 rows, 4 waves,
// LDS 34.8 KB (4 blocks/CU). Residual hb read stays ADJACENT to its write
// (r3 lesson). Floor is structure-insensitive (r4/r5/r6: 90.6/91.5/99.4 across
// 4-wave/2-wave/1-wave variants) — do not re-litigate without new counter evidence.
__global__ __launch_bounds__(256, 4) void k_mega(const unsigned short* __restrict__ agg,
                                                 const int* __restrict__ batch,
                                                 const float* __restrict__ c1,
                                                 const float* __restrict__ c0,
                                                 const unsigned short* __restrict__ W1,
                                                 const float* __restrict__ b1,
                                                 const unsigned short* __restrict__ W2,
                                                 const float* __restrict__ b2,
                                                 const unsigned short* __restrict__ Wc,
                                                 const float* __restrict__ dinv,
                                                 unsigned short* __restrict__ hb,
                                                 float* __restrict__ h_out,
                                                 unsigned short* __restrict__ y_out,
                                                 int writeF, int doConv) {
    __shared__ unsigned short ha_s[64 * 136];  // ha, then h' (pitch 136)
    __shared__ unsigned short ts[64 * 136];    // one 128-col half of t (pitch 136)
    const int tid = threadIdx.x;
    const int wave = tid >> 6;
    const int lane = tid & 63;
    const int quad = lane >> 4;
    const int l16 = lane & 15;
    const int rowBase = blockIdx.x * 64;
    const floatx4 zed = {0.f, 0.f, 0.f, 0.f};

    const int wrb = (wave & 1) << 5;   // 0/32
    const int wcb = (wave >> 1) << 6;  // 0/64
    const int co = wcb + (l16 << 2);

    // ---- phase 0: normswish -> ha_s ----
    {
        int lr = tid >> 2;           // 0..63
        int coff = (tid & 3) << 5;   // 0,32,64,96
        int r = rowBase + lr;
        if (r >= NN) r = NN - 1;
        int g = batch[r];
        const float* c1p = c1 + g * HH + coff;
        const float* c0p = c0 + g * HH + coff;
#pragma unroll
        for (int q = 0; q < 4; ++q) {
            uint4 raw = *(const uint4*)(agg + (size_t)r * HH + coff + (q << 3));
            float v[8];
            unpack8(raw, v);
            float4 ca = *(const float4*)(c1p + (q << 3));
            float4 cb4 = *(const float4*)(c1p + (q << 3) + 4);
            float4 da = *(const float4*)(c0p + (q << 3));
            float4 db = *(const float4*)(c0p + (q << 3) + 4);
            float cc1[8] = {ca.x, ca.y, ca.z, ca.w, cb4.x, cb4.y, cb4.z, cb4.w};
            float cc0[8] = {da.x, da.y, da.z, da.w, db.x, db.y, db.z, db.w};
            float o[8];
#pragma unroll
            for (int j = 0; j < 8; ++j) o[j] = swishf(cc1[j] * v[j] + cc0[j]);
            *(uint4*)(&ha_s[lr * 136 + coff + (q << 3)]) = pack8(o);
        }
    }
    __syncthreads();

    {
        floatx4 acc2[2][4];
#pragma unroll
        for (int i = 0; i < 2; ++i)
#pragma unroll
            for (int j = 0; j < 4; ++j) acc2[i][j] = zed;

#pragma unroll
        for (int h = 0; h < 2; ++h) {
            // ---- phase A half h: t[:, 128h+32w .. +32) = swish(ha @ W1^T + b1) ----
            floatx4 acc1[4][2];
#pragma unroll
            for (int i = 0; i < 4; ++i)
#pragma unroll
                for (int j = 0; j < 2; ++j) acc1[i][j] = zed;
            const int tcol = (wave << 5) + (l16 << 1);  // local col in half, 0..127
#pragma unroll
            for (int ks = 0; ks < 4; ++ks) {
                int k = (ks << 5) + (quad << 3);
                short8 a[4], b[2];
#pragma unroll
                for (int i = 0; i < 4; ++i)
                    a[i] = *(const short8*)(&ha_s[((i << 4) + l16) * 136 + k]);
#pragma unroll
                for (int j = 0; j < 2; ++j)
                    b[j] = *(const short8*)(W1 + (size_t)((h << 7) + tcol + j) * HH + k);
#pragma unroll
                for (int i = 0; i < 4; ++i)
#pragma unroll
                    for (int j = 0; j < 2; ++j)
                        acc1[i][j] = __builtin_amdgcn_mfma_f32_16x16x32_bf16(a[i], b[j],
                                                                             acc1[i][j], 0, 0, 0);
            }
            float2 bv = *(const float2*)(b1 + (h << 7) + tcol);
#pragma unroll
            for (int i = 0; i < 4; ++i) {
#pragma unroll
                for (int reg = 0; reg < 4; ++reg) {
                    int lr = (i << 4) + (quad << 2) + reg;
                    float o0 = swishf(acc1[i][0][reg] + bv.x);
                    float o1 = swishf(acc1[i][1][reg] + bv.y);
                    *(unsigned*)(&ts[lr * 136 + tcol]) = cvt2bf(o0, o1);
                }
            }
            __syncthreads();

            // ---- phase B half h: acc2 += t_h @ W2[:, 128h:+128]^T ----
#pragma unroll
            for (int ks = 0; ks < 4; ++ks) {
                int k = (ks << 5) + (quad << 3);
                short8 a[2], b[4];
#pragma unroll
                for (int i = 0; i < 2; ++i)
                    a[i] = *(const short8*)(&ts[(wrb + (i << 4) + l16) * 136 + k]);
#pragma unroll
                for (int j = 0; j < 4; ++j)
                    b[j] = *(const short8*)(W2 + (size_t)(wcb + (l16 << 2) + j) * MM +
                                            (h << 7) + k);
#pragma unroll
                for (int i = 0; i < 2; ++i)
#pragma unroll
                    for (int j = 0; j < 4; ++j)
                        acc2[i][j] = __builtin_amdgcn_mfma_f32_16x16x32_bf16(a[i], b[j],
                                                                             acc2[i][j], 0, 0, 0);
            }
            if (h == 0) __syncthreads();  // before next half overwrites ts
        }

        // ---- epilogue: h' = swish(acc2 + b2) + res ----
        float4 b4 = *(const float4*)(b2 + co);
        float bv[4] = {b4.x, b4.y, b4.z, b4.w};
#pragma unroll
        for (int i = 0; i < 2; ++i) {
#pragma unroll
            for (int reg = 0; reg < 4; ++reg) {
                int lr = wrb + (i << 4) + (quad << 2) + reg;
                int r = rowBase + lr;
                if (r < NN) {
                    uint2 rv = *(const uint2*)(hb + (size_t)r * HH + co);
                    float2 r01 = bf2f2(rv.x), r23 = bf2f2(rv.y);
                    float o[4];
                    o[0] = swishf(acc2[i][0][reg] + bv[0]) + r01.x;
                    o[1] = swishf(acc2[i][1][reg] + bv[1]) + r01.y;
                    o[2] = swishf(acc2[i][2][reg] + bv[2]) + r23.x;
                    o[3] = swishf(acc2[i][3][reg] + bv[3]) + r23.y;
                    if (doConv) {
                        uint2 pk = pack4(o);
                        *(uint2*)(hb + (size_t)r * HH + co) = pk;
                        *(uint2*)(&ha_s[lr * 136 + co]) = pk;
                    } else {
                        *(float4*)(h_out + (size_t)r * HH + co) =
                            make_float4(o[0], o[1], o[2], o[3]);
                    }
                } else if (doConv) {
                    *(uint2*)(&ha_s[lr * 136 + co]) = make_uint2(0u, 0u);
                }
            }
        }
    }

    // ---- phase C: y_next = bf16((h' @ Wc^T) * dinv) ----
    if (doConv) {
        __syncthreads();
        floatx4 acc3[2][4];
#pragma unroll
        for (int i = 0; i < 2; ++i)
#pragma unroll
            for (int j = 0; j < 4; ++j) acc3[i][j] = zed;
#pragma unroll
        for (int ks = 0; ks < 4; ++ks) {
            int k = (ks << 5) + (quad << 3);
            short8 a[2], b[4];
#pragma unroll
            for (int i = 0; i < 2; ++i)
                a[i] = *(const short8*)(&ha_s[(wrb + (i << 4) + l16) * 136 + k]);
#pragma unroll
            for (int j = 0; j < 4; ++j)
                b[j] = *(const short8*)(Wc + (size_t)(wcb + (l16 << 2) + j) * HH + k);
#pragma unroll
            for (int i = 0; i < 2; ++i)
#pragma unroll
                for (int j = 0; j < 4; ++j)
                    acc3[i][j] =
                        __builtin_amdgcn_mfma_f32_16x16x32_bf16(a[i], b[j], acc3[i][j], 0, 0, 0);
        }
#pragma unroll
        for (int i = 0; i < 2; ++i) {
#pragma unroll
            for (int reg = 0; reg < 4; ++reg) {
                int r = rowBase + wrb + (i << 4) + (quad << 2) + reg;
                if (r < NN) {
                    float dv = dinv[r];
                    float o[4];
#pragma unroll
                    for (int j = 0; j < 4; ++j) o[j] = acc3[i][j][reg] * dv;
                    *(uint2*)(y_out + (size_t)r * HH + co) = pack4(o);
                }
            }
        }
    }
}

extern "C" void kernel_launch(void* const* d_in, const int* in_sizes, int n_in,
                              void* d_out, int out_size, void* d_ws, size_t ws_size,
                              hipStream_t stream) {
    const float* x = (const float*)d_in[0];
    const int* ei = (const int*)d_in[1];
    const int* batch = (const int*)d_in[2];
    const float* z_embed = (const float*)d_in[3];
    const float* extra_w = (const float*)d_in[4];
    const float* extra_b = (const float*)d_in[5];
    const float* conv_w = (const float*)d_in[6];
    const float* conv_b = (const float*)d_in[7];
    const float* gamma = (const float*)d_in[8];
    const float* beta = (const float*)d_in[9];
    const float* mean_scale = (const float*)d_in[10];
    const float* mlp_w1 = (const float*)d_in[11];
    const float* mlp_b1 = (const float*)d_in[12];
    const float* mlp_w2 = (const float*)d_in[13];
    const float* mlp_b2 = (const float*)d_in[14];
    float* h_out = (float*)d_out;

    char* wsB = (char*)d_ws;
    size_t off = 0;
    auto alloc = [&](size_t bytes) -> void* {
        void* p = (void*)(wsB + off);
        off = (off + bytes + 255) & ~(size_t)255;
        return p;
    };
    float* dinv = (float*)alloc((size_t)NN * 4);
    int* deg = (int*)alloc((size_t)NN * 4);
    int* cursor = (int*)alloc((size_t)NN * 4);
    int* rowptr = (int*)alloc((size_t)(NN + 1) * 4);
    int* bsum = (int*)alloc(128 * 4);
    int* boff = (int*)alloc(128 * 4);
    int* col = (int*)alloc((size_t)EE * 4);
    int* gptr = (int*)alloc((size_t)(GG + 1) * 4);
    float* c1t = (float*)alloc((size_t)GG * HH * 4);
    float* c0t = (float*)alloc((size_t)GG * HH * 4);
    float* S1g6 = (float*)alloc((size_t)LL * GG * HH * 4);  // per-layer stats, zeroed once
    float* S2g6 = (float*)alloc((size_t)LL * GG * HH * 4);
    unsigned short* wb =
        (unsigned short*)alloc((size_t)(LL * (HH * HH + MM * HH + HH * MM)) * 2);
    unsigned short* cwb = wb;
    unsigned short* w1b = wb + (size_t)LL * HH * HH;
    unsigned short* w2b = w1b + (size_t)LL * MM * HH;
    unsigned short* hb = (unsigned short*)alloc((size_t)NN * HH * 2);    // bf16 residual
    unsigned short* ybuf = (unsigned short*)alloc((size_t)NN * HH * 2);  // y (conv out)
    unsigned short* aggb = (unsigned short*)alloc((size_t)NN * HH * 2);  // agg bf16

    hipMemsetAsync(deg, 0, (size_t)NN * 4, stream);
    hipMemsetAsync(cursor, 0, (size_t)NN * 4, stream);
    hipMemsetAsync(S1g6, 0, (size_t)LL * GG * HH * 4, stream);
    hipMemsetAsync(S2g6, 0, (size_t)LL * GG * HH * 4, stream);

    k_embed<<<(NN * 32 + 255) / 256, 256, 0, stream>>>(x, z_embed, extra_w, extra_b, hb);
    {
        int n1 = LL * HH * HH, n2 = LL * MM * HH, n3 = LL * HH * MM;
        int nt = n1 + n2 + n3;
        k_f2bf3<<<(nt + 255) / 256, 256, 0, stream>>>(conv_w, cwb, n1, mlp_w1, w1b, n2,
                                                      mlp_w2, w2b, n3);
    }
    k_degree_p<<<1024, 256, 0, stream>>>(ei + EE, deg);
    k_scan1<<<SCAN_NB, 256, 0, stream>>>(deg, bsum, dinv);
    k_scan2<<<1, 128, 0, stream>>>(bsum, boff);
    k_scan3<<<SCAN_NB, 256, 0, stream>>>(deg, boff, rowptr);
    k_fill_p<<<1024, 256, 0, stream>>>(ei, rowptr, cursor, col);
    k_gptr<<<(NN + 255) / 256, 256, 0, stream>>>(batch, gptr);

    int gconv = (NN + 127) / 128;
    int gmega = (NN + 63) / 64;
    k_conv<<<gconv, 256, 0, stream>>>(hb, cwb, dinv, ybuf);
    for (int i = 0; i < LL; ++i) {
        float* S1 = S1g6 + (size_t)i * GG * HH;
        float* S2 = S2g6 + (size_t)i * GG * HH;
        k_agg<<<NN / 16, 256, 0, stream>>>(ybuf, rowptr, col, dinv,
                                           conv_b + (size_t)i * HH, batch, aggb, S1, S2);
        k_finalize<<<GG, 128, 0, stream>>>(gptr, mean_scale + (size_t)i * HH,
                                           gamma + (size_t)i * HH, beta + (size_t)i * HH,
                                           S1, S2, c1t, c0t);
        k_mega<<<gmega, 256, 0, stream>>>(
            aggb, batch, c1t, c0t, w1b + (size_t)i * MM * HH, mlp_b1 + (size_t)i * MM,
            w2b + (size_t)i * HH * MM, mlp_b2 + (size_t)i * HH,
            cwb + (size_t)(i + 1 < LL ? i + 1 : 0) * HH * HH, dinv, hb, h_out, ybuf,
            i == LL - 1 ? 1 : 0, i < LL - 1 ? 1 : 0);
    }
}